// Round 2
// baseline (914.417 us; speedup 1.0000x reference)
//
#include <hip/hip_runtime.h>
#include <hip/hip_bf16.h>

typedef __hip_bfloat16 bf16;

#define ROWS 32768   // B*T = 128*256
#define NN 8
#define SDIM 200
#define DD 64
#define HYP 64
#define EMB 32
#define NN_OFF ((size_t)ROWS)                       // N_nn region start in d_out
#define EYE_OFF ((size_t)ROWS + (size_t)ROWS * 64)  // eye_mask region start

enum {
  I_QVALS, I_STATES, I_HID, I_EW1, I_EB1, I_EW2, I_EB2,
  I_WQ, I_BQ, I_WK, I_BK, I_WV, I_BV, I_WO, I_BO, I_L1G, I_L1B,
  I_FW1, I_FB1, I_FW2, I_FB2, I_L2G, I_L2B,
  I_NIW, I_NIB, I_NG, I_NB,
  I_W1A, I_B1A, I_W1B, I_B1B, I_HB1W, I_HB1B,
  I_W2A, I_B2A, I_W2B, I_B2B, I_HB2W1, I_HB2B1, I_HB2W2, I_HB2B2,
  NUM_IN
};

struct Params { const void* in[NUM_IN]; void* out; };

struct Smem {
    float sS[SDIM];       // states row
    float sQv[NN];        // qvals row
    float A[9][DD];       // h, later ffn hidden
    float Bq[9][DD];      // q, later attv
    float Ck[9][DD];      // k, later h2
    float Dv[9][DD];      // v, later h3
    float sAtt[9][12];    // attention scores / probs
    float sEns[2 * DD];   // ens (enc ++ mean(h_trans))
    float sNiRaw[NN][8];
    float sNiS[NN][8];
    float sNf[NN][NN];
    float sQni[NN];
    float sT[DD];         // t1 / t2 scratch
    float sW1[NN * EMB];
    float sB1[EMB];
    float sW2[EMB];
    float sSc[DD];
    float sB2s;
};

template<typename T> struct LDT;
template<> struct LDT<float> {
    static __device__ __forceinline__ float ld(const void* p, size_t i) { return ((const float*)p)[i]; }
    static __device__ __forceinline__ void st(void* p, size_t i, float v) { ((float*)p)[i] = v; }
};
template<> struct LDT<bf16> {
    static __device__ __forceinline__ float ld(const void* p, size_t i) { return __bfloat162float(((const bf16*)p)[i]); }
    static __device__ __forceinline__ void st(void* p, size_t i, float v) { ((bf16*)p)[i] = __float2bfloat16(v); }
};

template<typename T>
__device__ void mixer_body(const Params& p, Smem& sm, const int row, const int o) {
    using L = LDT<T>;

    // ---- stage 0: load states + qvals ----
    for (int k2 = o; k2 < SDIM; k2 += 64) sm.sS[k2] = L::ld(p.in[I_STATES], (size_t)row * SDIM + k2);
    if (o < NN) sm.sQv[o] = L::ld(p.in[I_QVALS], (size_t)row * NN + o);
    __syncthreads();

    // ---- stage 1: encoder MLP -> enc; build h ----
    {
        float a0 = 0.f, a1 = 0.f;
        for (int k2 = 0; k2 < SDIM; k2 += 2) {
            a0 += sm.sS[k2] * L::ld(p.in[I_EW1], k2 * DD + o);
            a1 += sm.sS[k2 + 1] * L::ld(p.in[I_EW1], (k2 + 1) * DD + o);
        }
        float e = fmaxf(a0 + a1 + L::ld(p.in[I_EB1], o), 0.f);
        sm.sT[o] = e;
        __syncthreads();
        float a = e + L::ld(p.in[I_EB2], o);
        for (int k2 = 0; k2 < DD; ++k2) a += sm.sT[k2] * L::ld(p.in[I_EW2], k2 * DD + o);
        float enc = tanhf(a);
        const size_t hbase = (size_t)row * (NN * DD) + o;
#pragma unroll
        for (int i = 0; i < NN; ++i) sm.A[i][o] = L::ld(p.in[I_HID], hbase + i * DD);
        sm.A[8][o] = enc;
        sm.sEns[o] = enc;
    }
    __syncthreads();

    // ---- stage 2: q, k, v = h @ {wq,wk,wv} + bias ----
    {
        float aq[9], ak[9], av[9];
        const float bqv = L::ld(p.in[I_BQ], o), bkv = L::ld(p.in[I_BK], o), bvv = L::ld(p.in[I_BV], o);
#pragma unroll
        for (int i = 0; i < 9; ++i) { aq[i] = bqv; ak[i] = bkv; av[i] = bvv; }
        for (int k2 = 0; k2 < DD; ++k2) {
            const float wqv = L::ld(p.in[I_WQ], k2 * DD + o);
            const float wkv = L::ld(p.in[I_WK], k2 * DD + o);
            const float wvv = L::ld(p.in[I_WV], k2 * DD + o);
#pragma unroll
            for (int i = 0; i < 9; ++i) {
                const float hv = sm.A[i][k2];
                aq[i] += hv * wqv; ak[i] += hv * wkv; av[i] += hv * wvv;
            }
        }
#pragma unroll
        for (int i = 0; i < 9; ++i) { sm.Bq[i][o] = aq[i]; sm.Ck[i][o] = ak[i]; sm.Dv[i][o] = av[i]; }
    }
    __syncthreads();

    // ---- stage 3: scores + softmax ----
    for (int pp = o; pp < 81; pp += 64) {
        const int i = pp / 9, j = pp - i * 9;
        float s = 0.f;
#pragma unroll 8
        for (int d2 = 0; d2 < DD; ++d2) s += sm.Bq[i][d2] * sm.Ck[j][d2];
        sm.sAtt[i][j] = s * 0.125f;
    }
    __syncthreads();
    if (o < 9) {
        float m = sm.sAtt[o][0];
#pragma unroll
        for (int j = 1; j < 9; ++j) m = fmaxf(m, sm.sAtt[o][j]);
        float ssum = 0.f;
#pragma unroll
        for (int j = 0; j < 9; ++j) { const float ex = __expf(sm.sAtt[o][j] - m); sm.sAtt[o][j] = ex; ssum += ex; }
        const float inv = 1.f / ssum;
#pragma unroll
        for (int j = 0; j < 9; ++j) sm.sAtt[o][j] *= inv;
    }
    __syncthreads();

    // ---- stage 4: attv = att@v -> o-proj -> residual + LN1 -> h2 (in Ck) ----
    {
        float attv[9];
#pragma unroll
        for (int i = 0; i < 9; ++i) {
            float a = 0.f;
#pragma unroll
            for (int j = 0; j < 9; ++j) a += sm.sAtt[i][j] * sm.Dv[j][o];
            attv[i] = a;
        }
        __syncthreads();
#pragma unroll
        for (int i = 0; i < 9; ++i) sm.Bq[i][o] = attv[i];  // Bq (q) dead
    }
    __syncthreads();
    {
        float h2p[9];
        const float bov = L::ld(p.in[I_BO], o);
#pragma unroll
        for (int i = 0; i < 9; ++i) h2p[i] = sm.A[i][o] + bov;
        for (int k2 = 0; k2 < DD; ++k2) {
            const float w = L::ld(p.in[I_WO], k2 * DD + o);
#pragma unroll
            for (int i = 0; i < 9; ++i) h2p[i] += sm.Bq[i][k2] * w;
        }
        const float g = L::ld(p.in[I_L1G], o), bb = L::ld(p.in[I_L1B], o);
        __syncthreads();
#pragma unroll
        for (int i = 0; i < 9; ++i) {
            const float x = h2p[i];
            float s = x, s2 = x * x;
#pragma unroll
            for (int off = 32; off > 0; off >>= 1) {
                s += __shfl_xor(s, off, 64);
                s2 += __shfl_xor(s2, off, 64);
            }
            const float mu = s * 0.015625f;
            const float var = s2 * 0.015625f - mu * mu;
            sm.Ck[i][o] = (x - mu) * rsqrtf(var + 1e-5f) * g + bb;  // Ck (k) dead
        }
    }
    __syncthreads();

    // ---- stage 5: FFN + residual + LN2 -> h3 (in Dv) ----
    {
        float fa[9];
        const float fb1 = L::ld(p.in[I_FB1], o);
#pragma unroll
        for (int i = 0; i < 9; ++i) fa[i] = fb1;
        for (int k2 = 0; k2 < DD; ++k2) {
            const float w = L::ld(p.in[I_FW1], k2 * DD + o);
#pragma unroll
            for (int i = 0; i < 9; ++i) fa[i] += sm.Ck[i][k2] * w;
        }
        __syncthreads();
#pragma unroll
        for (int i = 0; i < 9; ++i) sm.A[i][o] = fmaxf(fa[i], 0.f);  // A (h) dead
    }
    __syncthreads();
    {
        float h3p[9];
        const float fb2 = L::ld(p.in[I_FB2], o);
#pragma unroll
        for (int i = 0; i < 9; ++i) h3p[i] = sm.Ck[i][o] + fb2;
        for (int k2 = 0; k2 < DD; ++k2) {
            const float w = L::ld(p.in[I_FW2], k2 * DD + o);
#pragma unroll
            for (int i = 0; i < 9; ++i) h3p[i] += sm.A[i][k2] * w;
        }
        const float g = L::ld(p.in[I_L2G], o), bb = L::ld(p.in[I_L2B], o);
        __syncthreads();
#pragma unroll
        for (int i = 0; i < 9; ++i) {
            const float x = h3p[i];
            float s = x, s2 = x * x;
#pragma unroll
            for (int off = 32; off > 0; off >>= 1) {
                s += __shfl_xor(s, off, 64);
                s2 += __shfl_xor(s2, off, 64);
            }
            const float mu = s * 0.015625f;
            const float var = s2 * 0.015625f - mu * mu;
            sm.Dv[i][o] = (x - mu) * rsqrtf(var + 1e-5f) * g + bb;  // Dv (v) dead
        }
    }
    __syncthreads();

    // ---- stage 6: ens = [enc, mean_i(h_trans)] ----
    {
        float m = 0.f;
#pragma unroll
        for (int i = 0; i < NN; ++i) m += sm.Dv[i][o];
        sm.sEns[DD + o] = m * 0.125f;
    }
    __syncthreads();

    // ---- stage 7: ni = sigmoid(LN7(h_trans[n] @ fc2ni_w[n] + b)) ----
    {
        const int nn2 = o >> 3, ee = o & 7;
        float niv = 0.f;
        if (ee < 7) {
            niv = L::ld(p.in[I_NIB], nn2 * 7 + ee);
            const size_t wb = (size_t)nn2 * (DD * 7) + ee;
            for (int k2 = 0; k2 < DD; ++k2) niv += sm.Dv[nn2][k2] * L::ld(p.in[I_NIW], wb + k2 * 7);
        }
        sm.sNiRaw[nn2][ee] = niv;
        __syncthreads();
        if (ee < 7) {
            float s = 0.f, s2 = 0.f;
#pragma unroll
            for (int j = 0; j < 7; ++j) { const float x = sm.sNiRaw[nn2][j]; s += x; s2 += x * x; }
            const float inv7 = 1.f / 7.f;
            const float mu = s * inv7;
            const float var = s2 * inv7 - mu * mu;
            const float v = (niv - mu) * rsqrtf(var + 1e-5f) * L::ld(p.in[I_NG], ee) + L::ld(p.in[I_NB], ee);
            sm.sNiS[nn2][ee] = 1.f / (1.f + __expf(-v));
        }
    }
    __syncthreads();

    // ---- stage 8: nfull + write N_nn / eye_mask; q_ni ----
    {
        const int i = o >> 3, j = o & 7;
        float nf;
        if (i == j) nf = 1.f;
        else nf = sm.sNiS[i][j - (j > i ? 1 : 0)];
        sm.sNf[i][j] = nf;
        L::st(p.out, NN_OFF + (size_t)row * 64 + o, nf);
        L::st(p.out, EYE_OFF + (size_t)row * 64 + o, i == j ? 1.f : 0.f);
    }
    __syncthreads();
    if (o < NN) {
        float s = 0.f;
#pragma unroll
        for (int j = 0; j < NN; ++j) s += sm.sQv[j] * sm.sNf[o][j];
        sm.sQni[o] = s;
    }
    __syncthreads();

    // ---- stage 10a: t1 = relu(ens@w1a+b1a); w1 = |t1@w1b+b1b| ----
    {
        float a = L::ld(p.in[I_B1A], o);
        for (int k2 = 0; k2 < 2 * DD; ++k2) a += sm.sEns[k2] * L::ld(p.in[I_W1A], k2 * HYP + o);
        sm.sT[o] = fmaxf(a, 0.f);
    }
    __syncthreads();
    {
        float a0 = L::ld(p.in[I_B1B], o),       a1 = L::ld(p.in[I_B1B], o + 64);
        float a2 = L::ld(p.in[I_B1B], o + 128), a3 = L::ld(p.in[I_B1B], o + 192);
        for (int k2 = 0; k2 < DD; ++k2) {
            const float t = sm.sT[k2];
            const size_t wb = (size_t)k2 * 256 + o;
            a0 += t * L::ld(p.in[I_W1B], wb);       a1 += t * L::ld(p.in[I_W1B], wb + 64);
            a2 += t * L::ld(p.in[I_W1B], wb + 128); a3 += t * L::ld(p.in[I_W1B], wb + 192);
        }
        sm.sW1[o] = fabsf(a0); sm.sW1[o + 64] = fabsf(a1);
        sm.sW1[o + 128] = fabsf(a2); sm.sW1[o + 192] = fabsf(a3);
    }
    // ---- stage 10b: b1 = ens@hb1w + hb1b ----
    {
        const int c = o & 31, hh = o >> 5;
        float a = 0.f;
        const int k0 = hh * DD;
        for (int k2 = 0; k2 < DD; ++k2) a += sm.sEns[k0 + k2] * L::ld(p.in[I_HB1W], (k0 + k2) * EMB + c);
        sm.sSc[o] = a;
    }
    __syncthreads();
    if (o < EMB) sm.sB1[o] = sm.sSc[o] + sm.sSc[o + 32] + L::ld(p.in[I_HB1B], o);
    __syncthreads();
    // ---- stage 10c: t2 = relu(ens@w2a+b2a); w2 = |t2@w2b+b2b| ----
    {
        float a = L::ld(p.in[I_B2A], o);
        for (int k2 = 0; k2 < 2 * DD; ++k2) a += sm.sEns[k2] * L::ld(p.in[I_W2A], k2 * HYP + o);
        __syncthreads();
        sm.sT[o] = fmaxf(a, 0.f);
    }
    __syncthreads();
    {
        const int c = o & 31, hh = o >> 5;
        float a = 0.f;
        const int k0 = hh * 32;
        for (int k2 = 0; k2 < 32; ++k2) a += sm.sT[k0 + k2] * L::ld(p.in[I_W2B], (k0 + k2) * EMB + c);
        sm.sSc[o] = a;
    }
    __syncthreads();
    if (o < EMB) sm.sW2[o] = fabsf(sm.sSc[o] + sm.sSc[o + 32] + L::ld(p.in[I_B2B], o));
    __syncthreads();
    // ---- stage 10d: b2 = relu(ens@hb2w1+hb2b1)@hb2w2 + hb2b2 ----
    {
        const int c = o & 31, hh = o >> 5;
        float a = 0.f;
        const int k0 = hh * DD;
        for (int k2 = 0; k2 < DD; ++k2) a += sm.sEns[k0 + k2] * L::ld(p.in[I_HB2W1], (k0 + k2) * EMB + c);
        sm.sSc[o] = a;
    }
    __syncthreads();
    if (o < EMB) {
        const float t3 = fmaxf(sm.sSc[o] + sm.sSc[o + 32] + L::ld(p.in[I_HB2B1], o), 0.f);
        sm.sSc[o] = t3 * L::ld(p.in[I_HB2W2], o);
    }
    __syncthreads();
    if (o == 0) {
        float s = 0.f;
#pragma unroll
        for (int e = 0; e < EMB; ++e) s += sm.sSc[e];
        sm.sB2s = s + L::ld(p.in[I_HB2B2], 0);
    }
    __syncthreads();

    // ---- stage 11: hidden = elu(q_ni@w1 + b1); y = hidden@w2 + b2 ----
    if (o < EMB) {
        float a = sm.sB1[o];
#pragma unroll
        for (int i = 0; i < NN; ++i) a += sm.sQni[i] * sm.sW1[i * EMB + o];
        const float hid = a > 0.f ? a : (__expf(a) - 1.f);
        sm.sSc[o] = hid * sm.sW2[o];
    }
    __syncthreads();
    if (o == 0) {
        float s = 0.f;
#pragma unroll
        for (int e = 0; e < EMB; ++e) s += sm.sSc[e];
        L::st(p.out, row, s + sm.sB2s);
    }
}

// One wave (64 threads) per (b,t) row. Lane index = feature dim o (0..63).
// Dtype self-sniff: if inputs are f32 misread as bf16, the 32 low-half u16s of
// the first 32 floats have near-uniform exponent bits -> ~28/64 "wild"; if
// inputs are genuine bf16 (values ~N(0,1)), wild count ~0. Threshold 8.
__global__ __launch_bounds__(64) void mixer_kernel(Params p) {
    extern __shared__ char smraw[];
    Smem& sm = *reinterpret_cast<Smem*>(smraw);
    const int row = blockIdx.x;
    const int o = threadIdx.x;

    const unsigned short bits = ((const unsigned short*)p.in[I_STATES])[o];
    const int e = (bits >> 7) & 0xFF;
    const bool wild = (e > 140) || (e > 0 && e < 110);
    const int nw = __popcll(__ballot(wild));
    if (nw >= 8) mixer_body<float>(p, sm, row, o);
    else         mixer_body<bf16>(p, sm, row, o);
}

extern "C" void kernel_launch(void* const* d_in, const int* in_sizes, int n_in,
                              void* d_out, int out_size, void* d_ws, size_t ws_size,
                              hipStream_t stream) {
    Params p;
    for (int i = 0; i < NUM_IN; ++i) p.in[i] = d_in[i];
    p.out = d_out;
    mixer_kernel<<<ROWS, 64, sizeof(Smem), stream>>>(p);
}

// Round 5
// 439.423 us; speedup vs baseline: 2.0809x; 2.0809x over previous
//
#include <hip/hip_runtime.h>
#include <hip/hip_bf16.h>

typedef __bf16 bf16x8 __attribute__((ext_vector_type(8)));
typedef __bf16 bf16x4 __attribute__((ext_vector_type(4)));
typedef float f32x4 __attribute__((ext_vector_type(4)));

#define ROWSG 32768          // B*T
#define RB 8                 // bt rows per block
#define HPAD 72              // bf16 row stride (16B-aligned, bank-staggered)
#define NN_OFF ((size_t)ROWSG)
#define EYE_OFF ((size_t)ROWSG + (size_t)ROWSG*64)

// weight-cache offsets (bf16 elements), all WT[n][k] row-major, stride = Kp
#define OFF_EW1   0          // 64 x 224 (K=200 zero-padded)
#define OFF_EW2   14336      // 64 x 64
#define OFF_WQ    18432
#define OFF_WK    22528
#define OFF_WV    26624
#define OFF_WO    30720
#define OFF_F1    34816
#define OFF_F2    38912
#define OFF_W1A   43008      // 64 x 128
#define OFF_W1B   51200      // 256 x 64
#define OFF_HB1W  67584      // 32 x 128
#define OFF_W2A   71680      // 64 x 128
#define OFF_W2B   79872      // 32 x 64
#define OFF_HB2W1 81920      // 32 x 128
#define WS_TOTAL  86016

// Module-scope device array: avoids any dependence on harness ws_size.
__device__ __align__(16) __bf16 g_ws[WS_TOTAL];

#define MFMA16(a,b,c) __builtin_amdgcn_mfma_f32_16x16x32_bf16(a,b,c,0,0,0)

// ---------------- weight transform kernel ----------------
struct TP { const float* src[14]; };

__global__ __launch_bounds__(256) void wtrans(TP tp) {
    const int gid = blockIdx.x * 256 + threadIdx.x;
    if (gid >= WS_TOTAL) return;
    const int OFFS[14] = {OFF_EW1, OFF_EW2, OFF_WQ, OFF_WK, OFF_WV, OFF_WO, OFF_F1,
                          OFF_F2, OFF_W1A, OFF_W1B, OFF_HB1W, OFF_W2A, OFF_W2B, OFF_HB2W1};
    const int KPS[14]  = {224, 64, 64, 64, 64, 64, 64, 64, 128, 64, 128, 128, 64, 128};
    const int KRS[14]  = {200, 64, 64, 64, 64, 64, 64, 64, 128, 64, 128, 128, 64, 128};
    const int NS[14]   = {64, 64, 64, 64, 64, 64, 64, 64, 64, 256, 32, 64, 32, 32};
    int m = 0;
#pragma unroll
    for (int i = 1; i < 14; ++i) if (gid >= OFFS[i]) m = i;
    const int loc = gid - OFFS[m];
    const int Kp = KPS[m];
    const int n = loc / Kp;
    const int k = loc - n * Kp;
    float v = 0.f;
    if (k < KRS[m]) v = tp.src[m][(size_t)k * NS[m] + n];   // src is W[k][n]
    g_ws[gid] = (__bf16)v;
}

// ---------------- main fused kernel ----------------
struct MainP {
    const float *qvals, *states, *hid, *eb1, *eb2, *bq, *bk, *bv, *bo,
        *l1g, *l1b, *fb1, *fb2, *l2g, *l2b, *niw, *nib, *ng, *nb,
        *b1a, *b1b, *hb1b, *b2a, *b2b, *hb2b1, *hw2, *hb2b2;
    float* out;
};

// fused projection + bias + residual + LayerNorm, in MFMA C/D register layout.
// A: activation (stride HPAD), WT: weights [n][64], H: residual in / LN out.
__device__ __forceinline__ void proj_ln(const __bf16* A, const __bf16* WT,
                                        const float* bias, const float* g, const float* bb,
                                        __bf16* H, int w, int quad, int l15) {
    for (int mti = 0; mti < 2; ++mti) {
        const int mt = w + 4 * mti;          // wave-uniform
        if (mt >= 5) continue;
        f32x4 acc0 = {0,0,0,0}, acc1 = {0,0,0,0}, acc2 = {0,0,0,0}, acc3 = {0,0,0,0};
#pragma unroll
        for (int ks = 0; ks < 2; ++ks) {
            const int kk = ks * 32 + quad * 8;
            const bf16x8 af = *(const bf16x8*)(A + (mt * 16 + l15) * HPAD + kk);
            acc0 = MFMA16(af, *(const bf16x8*)(WT + (size_t)(0 * 16 + l15) * 64 + kk), acc0);
            acc1 = MFMA16(af, *(const bf16x8*)(WT + (size_t)(1 * 16 + l15) * 64 + kk), acc1);
            acc2 = MFMA16(af, *(const bf16x8*)(WT + (size_t)(2 * 16 + l15) * 64 + kk), acc2);
            acc3 = MFMA16(af, *(const bf16x8*)(WT + (size_t)(3 * 16 + l15) * 64 + kk), acc3);
        }
        float v[4][4], g4[4], b4[4];
#pragma unroll
        for (int nt = 0; nt < 4; ++nt) {
            const int col = nt * 16 + l15;
            const float bo = bias[col];
            g4[nt] = g[col]; b4[nt] = bb[col];
            const f32x4 a = (nt == 0) ? acc0 : (nt == 1) ? acc1 : (nt == 2) ? acc2 : acc3;
#pragma unroll
            for (int r = 0; r < 4; ++r)
                v[nt][r] = a[r] + bo + (float)H[(mt * 16 + quad * 4 + r) * HPAD + col];
        }
#pragma unroll
        for (int r = 0; r < 4; ++r) {
            float s  = v[0][r] + v[1][r] + v[2][r] + v[3][r];
            float s2 = v[0][r]*v[0][r] + v[1][r]*v[1][r] + v[2][r]*v[2][r] + v[3][r]*v[3][r];
#pragma unroll
            for (int off = 1; off < 16; off <<= 1) {
                s  += __shfl_xor(s,  off, 64);
                s2 += __shfl_xor(s2, off, 64);
            }
            const float mu  = s * 0.015625f;
            const float var = s2 * 0.015625f - mu * mu;
            const float rs  = rsqrtf(var + 1e-5f);
#pragma unroll
            for (int nt = 0; nt < 4; ++nt)
                H[(mt * 16 + quad * 4 + r) * HPAD + nt * 16 + l15] =
                    (__bf16)((v[nt][r] - mu) * rs * g4[nt] + b4[nt]);
        }
    }
}

__global__ __launch_bounds__(256) void mixer_main(MainP p) {
    __shared__ __bf16 Qb[80 * HPAD];    // q -> attv
    __shared__ __bf16 Kb[80 * HPAD];    // k -> ffn hidden
    __shared__ __bf16 Vb[80 * HPAD];    // v
    __shared__ __bf16 Hb[80 * HPAD];    // h -> h2 -> h3
    __shared__ __bf16 EbU[16 * HPAD];   // Eb -> sNi(float[512]) -> Tb1
    __shared__ __bf16 Tb2[16 * HPAD];
    __shared__ __bf16 ensB[16 * 136];
    __shared__ float  attU[8 * 81];     // att probs -> Nf(float[512])
    __shared__ float  sQv[64];
    __shared__ float  qniL[64];
    __shared__ __bf16 W1bS[8 * 256];
    __shared__ float  B1f[8 * 32], W2f[8 * 32], T3f[8 * 32];

    const int blk = blockIdx.x;
    const int bt0 = blk * RB;
    const int t = threadIdx.x;
    const int w = t >> 6, lane = t & 63, quad = lane >> 4, l15 = lane & 15;
    const __bf16* ws = g_ws;

    // ---- P0: stage hidden_state -> Hb rows x*9+n; qvals -> sQv ----
    // RB*512 floats = 1024 float4 units = 4 iterations of 256 threads.
    // (round-3/4 abort root cause: this loop ran 8 iters -> x up to 15 -> OOB
    //  global read past hidden_state for the tail blocks.)
#pragma unroll
    for (int it = 0; it < 4; ++it) {
        const int u = it * 256 + t;               // 1024 float4 units
        const int x = u >> 7, rem = u & 127, n = rem >> 4, d4 = (rem & 15) * 4;
        const float4 v4 = *(const float4*)(p.hid + ((size_t)(bt0 + x) * 512 + n * 64 + d4));
        bf16x4 o; o[0] = (__bf16)v4.x; o[1] = (__bf16)v4.y; o[2] = (__bf16)v4.z; o[3] = (__bf16)v4.w;
        *(bf16x4*)(Hb + (x * 9 + n) * HPAD + d4) = o;
    }
    if (t < 64) sQv[t] = p.qvals[(size_t)(bt0 + (t >> 3)) * 8 + (t & 7)];
    __syncthreads();

    // ---- P1: encoder layer 1 (M=16 padded, K=200->224, N=64; wave w owns n-tile w) ----
    float e4[4];
    {
        const int n0 = w * 16;
        int srow = bt0 + l15; if (srow >= ROWSG) srow = ROWSG - 1;
        const float* sp0 = p.states + (size_t)srow * 200;
        f32x4 acc = {0, 0, 0, 0};
        for (int ks = 0; ks < 7; ++ks) {
            const int kk = ks * 32 + quad * 8;
            bf16x8 af;
            if (kk < 200) {
#pragma unroll
                for (int j = 0; j < 8; ++j) af[j] = (__bf16)sp0[kk + j];
            } else {
#pragma unroll
                for (int j = 0; j < 8; ++j) af[j] = (__bf16)0.0f;
            }
            const bf16x8 bf = *(const bf16x8*)(ws + OFF_EW1 + (size_t)(n0 + l15) * 224 + kk);
            acc = MFMA16(af, bf, acc);
        }
        const float b1 = p.eb1[n0 + l15];
#pragma unroll
        for (int r = 0; r < 4; ++r) {
            const float ev = fmaxf(acc[r] + b1, 0.f);
            e4[r] = ev;
            EbU[(quad * 4 + r) * HPAD + n0 + l15] = (__bf16)ev;
        }
    }
    __syncthreads();

    // ---- P2: encoder layer 2: enc = tanh(e@W2 + e + b2) -> Hb row x*9+8, ensB[:,0:64] ----
    {
        const int n0 = w * 16;
        f32x4 acc = {0, 0, 0, 0};
#pragma unroll
        for (int ks = 0; ks < 2; ++ks) {
            const int kk = ks * 32 + quad * 8;
            const bf16x8 af = *(const bf16x8*)(EbU + l15 * HPAD + kk);
            const bf16x8 bf = *(const bf16x8*)(ws + OFF_EW2 + (size_t)(n0 + l15) * 64 + kk);
            acc = MFMA16(af, bf, acc);
        }
        const float b2 = p.eb2[n0 + l15];
#pragma unroll
        for (int r = 0; r < 4; ++r) {
            const int xr = quad * 4 + r;
            if (xr < RB) {
                const float ev = tanhf(acc[r] + e4[r] + b2);
                Hb[(xr * 9 + 8) * HPAD + n0 + l15] = (__bf16)ev;
                ensB[xr * 136 + n0 + l15] = (__bf16)ev;
            }
        }
    }
    __syncthreads();

    // ---- P3: Q,K,V projections (60 tile-jobs, 15 per wave) ----
    for (int it = 0; it < 15; ++it) {
        const int j = w + 4 * it;                 // 0..59
        const int mat = j / 20, r20 = j % 20, mt = r20 >> 2, nt = r20 & 3;
        const __bf16* wt = ws + (mat == 0 ? OFF_WQ : mat == 1 ? OFF_WK : OFF_WV);
        const float* bias = (mat == 0 ? p.bq : mat == 1 ? p.bk : p.bv);
        __bf16* dst = (mat == 0 ? Qb : mat == 1 ? Kb : Vb);
        f32x4 acc = {0, 0, 0, 0};
#pragma unroll
        for (int ks = 0; ks < 2; ++ks) {
            const int kk = ks * 32 + quad * 8;
            const bf16x8 af = *(const bf16x8*)(Hb + (mt * 16 + l15) * HPAD + kk);
            const bf16x8 bf = *(const bf16x8*)(wt + (size_t)(nt * 16 + l15) * 64 + kk);
            acc = MFMA16(af, bf, acc);
        }
        const float bv = bias[nt * 16 + l15];
#pragma unroll
        for (int r = 0; r < 4; ++r)
            dst[(mt * 16 + quad * 4 + r) * HPAD + nt * 16 + l15] = (__bf16)(acc[r] + bv);
    }
    __syncthreads();

    // ---- P4: scores (wave w -> bts 2w,2w+1), then softmax ----
    for (int xi = 0; xi < 2; ++xi) {
        const int x = w * 2 + xi;
        for (int base = 0; base < 81; base += 64) {
            const int pidx = base + lane;
            if (pidx < 81) {
                const int i = pidx / 9, jj = pidx - (pidx / 9) * 9;
                const __bf16* qr = Qb + (x * 9 + i) * HPAD;
                const __bf16* kr = Kb + (x * 9 + jj) * HPAD;
                float s = 0.f;
#pragma unroll
                for (int d = 0; d < 64; d += 2) {
                    const unsigned qu = *(const unsigned*)(qr + d);
                    const unsigned ku = *(const unsigned*)(kr + d);
                    const float qlo = __uint_as_float(qu << 16);
                    const float qhi = __uint_as_float(qu & 0xffff0000u);
                    const float klo = __uint_as_float(ku << 16);
                    const float khi = __uint_as_float(ku & 0xffff0000u);
                    s += qlo * klo + qhi * khi;
                }
                attU[x * 81 + pidx] = s * 0.125f;
            }
        }
    }
    __syncthreads();
    if (t < 72) {
        const int x = t / 9, i = t - (t / 9) * 9;
        float* ar = attU + x * 81 + i * 9;
        float m = ar[0];
#pragma unroll
        for (int j = 1; j < 9; ++j) m = fmaxf(m, ar[j]);
        float ssum = 0.f;
#pragma unroll
        for (int j = 0; j < 9; ++j) { const float ex = __expf(ar[j] - m); ar[j] = ex; ssum += ex; }
        const float inv = 1.f / ssum;
#pragma unroll
        for (int j = 0; j < 9; ++j) ar[j] *= inv;
    }
    __syncthreads();

    // ---- P5: attv = att @ v -> overwrite Qb (bf16); lane = d ----
    for (int xi = 0; xi < 2; ++xi) {
        const int x = w * 2 + xi;
        float vreg[9];
#pragma unroll
        for (int jj = 0; jj < 9; ++jj) vreg[jj] = (float)Vb[(x * 9 + jj) * HPAD + lane];
#pragma unroll
        for (int i = 0; i < 9; ++i) {
            float a = 0.f;
#pragma unroll
            for (int jj = 0; jj < 9; ++jj) a += attU[x * 81 + i * 9 + jj] * vreg[jj];
            Qb[(x * 9 + i) * HPAD + lane] = (__bf16)a;
        }
    }
    __syncthreads();

    // ---- P6: o-proj + residual(h) + LN1 -> h2 in Hb ----
    proj_ln(Qb, ws + OFF_WO, p.bo, p.l1g, p.l1b, Hb, w, quad, l15);
    __syncthreads();

    // ---- P7: FFN1: f = relu(h2@W1 + b1) -> Kb ----
    for (int it = 0; it < 5; ++it) {
        const int j = w + 4 * it;                 // 0..19
        const int mt = j >> 2, nt = j & 3;
        f32x4 acc = {0, 0, 0, 0};
#pragma unroll
        for (int ks = 0; ks < 2; ++ks) {
            const int kk = ks * 32 + quad * 8;
            const bf16x8 af = *(const bf16x8*)(Hb + (mt * 16 + l15) * HPAD + kk);
            const bf16x8 bf = *(const bf16x8*)(ws + OFF_F1 + (size_t)(nt * 16 + l15) * 64 + kk);
            acc = MFMA16(af, bf, acc);
        }
        const float fb = p.fb1[nt * 16 + l15];
#pragma unroll
        for (int r = 0; r < 4; ++r)
            Kb[(mt * 16 + quad * 4 + r) * HPAD + nt * 16 + l15] = (__bf16)fmaxf(acc[r] + fb, 0.f);
    }
    __syncthreads();

    // ---- P8: FFN2 + residual(h2) + LN2 -> h3 in Hb ----
    proj_ln(Kb, ws + OFF_F2, p.fb2, p.l2g, p.l2b, Hb, w, quad, l15);
    __syncthreads();

    // ---- P8b: ens second half = mean over 8 heads of h3 ----
#pragma unroll
    for (int it = 0; it < 2; ++it) {
        const int id = it * 256 + t;
        const int x = id >> 6, col = id & 63;
        float s = 0.f;
#pragma unroll
        for (int i = 0; i < 8; ++i) s += (float)Hb[(x * 9 + i) * HPAD + col];
        ensB[x * 136 + 64 + col] = (__bf16)(s * 0.125f);
    }
    __syncthreads();

    // ---- P9: ni = sigmoid(LN7(h3[:, :8]@fc2ni + b)); 4 threads per (x,n) split over d ----
    {
        const int pr = t >> 2, q4 = t & 3;
        const int x = pr >> 3, n = pr & 7;
        float acc[7] = {0.f, 0.f, 0.f, 0.f, 0.f, 0.f, 0.f};
        const float* wni = p.niw + n * 448;
        for (int dd = 0; dd < 16; ++dd) {
            const int d = q4 * 16 + dd;
            const float hv = (float)Hb[(x * 9 + n) * HPAD + d];
#pragma unroll
            for (int e = 0; e < 7; ++e) acc[e] += hv * wni[d * 7 + e];
        }
#pragma unroll
        for (int e = 0; e < 7; ++e) {
            acc[e] += __shfl_xor(acc[e], 1, 64);
            acc[e] += __shfl_xor(acc[e], 2, 64);
        }
        if (q4 == 0) {
            float s = 0.f;
#pragma unroll
            for (int e = 0; e < 7; ++e) { acc[e] += p.nib[n * 7 + e]; s += acc[e]; }
            const float mu = s * (1.f / 7.f);
            float s2 = 0.f;
#pragma unroll
            for (int e = 0; e < 7; ++e) { const float d0 = acc[e] - mu; s2 += d0 * d0; }
            const float rs = rsqrtf(s2 * (1.f / 7.f) + 1e-5f);
            float* sNi = (float*)EbU;
#pragma unroll
            for (int e = 0; e < 7; ++e) {
                const float vv = (acc[e] - mu) * rs * p.ng[e] + p.nb[e];
                sNi[x * 64 + n * 8 + e] = 1.f / (1.f + __expf(-vv));
            }
        }
    }
    __syncthreads();

    // ---- P9b: N_nn + eye_mask outputs, then q_ni ----
    {
        const float* sNi = (const float*)EbU;
        float* Nf = attU;                        // att dead; 512 floats fit in 648
#pragma unroll
        for (int it = 0; it < 2; ++it) {
            const int id = it * 256 + t;
            const int x = id >> 6, rem = id & 63, i = rem >> 3, jj = rem & 7;
            const float nf = (i == jj) ? 1.f : sNi[x * 64 + i * 8 + (jj - (jj > i ? 1 : 0))];
            p.out[NN_OFF + (size_t)(bt0 + x) * 64 + rem] = nf;
            p.out[EYE_OFF + (size_t)(bt0 + x) * 64 + rem] = (i == jj) ? 1.f : 0.f;
            Nf[x * 64 + rem] = nf;
        }
    }
    __syncthreads();
    {
        const float* Nf = attU;
        const int pr = t >> 2, q4 = t & 3;
        const int x = pr >> 3, i = pr & 7;
        const int j0 = q4 * 2;
        float s = sQv[x * 8 + j0] * Nf[x * 64 + i * 8 + j0] +
                  sQv[x * 8 + j0 + 1] * Nf[x * 64 + i * 8 + j0 + 1];
        s += __shfl_xor(s, 1, 64);
        s += __shfl_xor(s, 2, 64);
        if (q4 == 0) qniL[x * 8 + i] = s;
    }
    __syncthreads();

    // ---- P10 sub1: t1 = relu(ens@w1a+b1a) -> Tb1(EbU); t2 = relu(ens@w2a+b2a) -> Tb2 ----
    {
        const int n0 = w * 16;
#pragma unroll
        for (int m2 = 0; m2 < 2; ++m2) {
            const __bf16* wt = ws + (m2 == 0 ? OFF_W1A : OFF_W2A);
            const float* bias = m2 == 0 ? p.b1a : p.b2a;
            __bf16* dst = m2 == 0 ? EbU : Tb2;
            f32x4 acc = {0, 0, 0, 0};
#pragma unroll
            for (int ks = 0; ks < 4; ++ks) {
                const int kk = ks * 32 + quad * 8;
                const bf16x8 af = *(const bf16x8*)(ensB + l15 * 136 + kk);
                const bf16x8 bf = *(const bf16x8*)(wt + (size_t)(n0 + l15) * 128 + kk);
                acc = MFMA16(af, bf, acc);
            }
            const float bb = bias[n0 + l15];
#pragma unroll
            for (int r = 0; r < 4; ++r)
                dst[(quad * 4 + r) * HPAD + n0 + l15] = (__bf16)fmaxf(acc[r] + bb, 0.f);
        }
    }
    __syncthreads();

    // ---- P10 sub2: w1 (16 jobs), b1 (2), w2 (2), t3 (2) = 22 tile-jobs ----
    for (int it = 0; it < 6; ++it) {
        const int j = w + 4 * it;
        if (j >= 22) continue;
        int mode, n0, Kp, ksteps, aStride;
        const __bf16 *A, *WT; const float* bias;
        if (j < 16)      { mode = 0; n0 = j * 16;        A = EbU;  aStride = HPAD; WT = ws + OFF_W1B;   bias = p.b1b;  Kp = 64;  ksteps = 2; }
        else if (j < 18) { mode = 1; n0 = (j - 16) * 16; A = ensB; aStride = 136;  WT = ws + OFF_HB1W;  bias = p.hb1b; Kp = 128; ksteps = 4; }
        else if (j < 20) { mode = 2; n0 = (j - 18) * 16; A = Tb2;  aStride = HPAD; WT = ws + OFF_W2B;   bias = p.b2b;  Kp = 64;  ksteps = 2; }
        else             { mode = 3; n0 = (j - 20) * 16; A = ensB; aStride = 136;  WT = ws + OFF_HB2W1; bias = p.hb2b1;Kp = 128; ksteps = 4; }
        f32x4 acc = {0, 0, 0, 0};
        for (int ks = 0; ks < ksteps; ++ks) {
            const int kk = ks * 32 + quad * 8;
            const bf16x8 af = *(const bf16x8*)(A + l15 * aStride + kk);
            const bf16x8 bf = *(const bf16x8*)(WT + (size_t)(n0 + l15) * Kp + kk);
            acc = MFMA16(af, bf, acc);
        }
        const float bb = bias[n0 + l15];
#pragma unroll
        for (int r = 0; r < 4; ++r) {
            const int xr = quad * 4 + r;
            if (xr < RB) {
                const float val = acc[r] + bb;
                if (mode == 0)      W1bS[xr * 256 + n0 + l15] = (__bf16)fabsf(val);
                else if (mode == 1) B1f[xr * 32 + n0 + l15] = val;
                else if (mode == 2) W2f[xr * 32 + n0 + l15] = fabsf(val);
                else                T3f[xr * 32 + n0 + l15] = fmaxf(val, 0.f);
            }
        }
    }
    __syncthreads();

    // ---- P11: hidden = elu(q_ni@w1 + b1); y = hidden@w2 + b2 ----
    if (t < 128) {
        const int x = t >> 4, sub = t & 15;
        float pp = 0.f, pb = 0.f;
#pragma unroll
        for (int h2i = 0; h2i < 2; ++h2i) {
            const int e = sub + h2i * 16;
            float a = B1f[x * 32 + e];
#pragma unroll
            for (int i = 0; i < 8; ++i) a += qniL[x * 8 + i] * (float)W1bS[x * 256 + i * 32 + e];
            const float hid = a > 0.f ? a : (__expf(a) - 1.f);
            pp += hid * W2f[x * 32 + e];
            pb += T3f[x * 32 + e] * p.hw2[e];
        }
#pragma unroll
        for (int off = 1; off < 16; off <<= 1) {
            pp += __shfl_xor(pp, off, 64);
            pb += __shfl_xor(pb, off, 64);
        }
        if (sub == 0) p.out[bt0 + x] = pp + pb + p.hb2b2[0];
    }
}

extern "C" void kernel_launch(void* const* d_in, const int* in_sizes, int n_in,
                              void* d_out, int out_size, void* d_ws, size_t ws_size,
                              hipStream_t stream) {
    TP tp;
    tp.src[0]  = (const float*)d_in[3];   // enc_w1
    tp.src[1]  = (const float*)d_in[5];   // enc_w2
    tp.src[2]  = (const float*)d_in[7];   // wq
    tp.src[3]  = (const float*)d_in[9];   // wk
    tp.src[4]  = (const float*)d_in[11];  // wv
    tp.src[5]  = (const float*)d_in[13];  // wo
    tp.src[6]  = (const float*)d_in[17];  // ffn_w1
    tp.src[7]  = (const float*)d_in[19];  // ffn_w2
    tp.src[8]  = (const float*)d_in[27];  // w1a
    tp.src[9]  = (const float*)d_in[29];  // w1b
    tp.src[10] = (const float*)d_in[31];  // hb1w
    tp.src[11] = (const float*)d_in[33];  // w2a
    tp.src[12] = (const float*)d_in[35];  // w2b
    tp.src[13] = (const float*)d_in[37];  // hb2w1
    wtrans<<<(WS_TOTAL + 255) / 256, 256, 0, stream>>>(tp);

    MainP p;
    p.qvals = (const float*)d_in[0];
    p.states = (const float*)d_in[1];
    p.hid = (const float*)d_in[2];
    p.eb1 = (const float*)d_in[4];
    p.eb2 = (const float*)d_in[6];
    p.bq = (const float*)d_in[8];
    p.bk = (const float*)d_in[10];
    p.bv = (const float*)d_in[12];
    p.bo = (const float*)d_in[14];
    p.l1g = (const float*)d_in[15];
    p.l1b = (const float*)d_in[16];
    p.fb1 = (const float*)d_in[18];
    p.fb2 = (const float*)d_in[20];
    p.l2g = (const float*)d_in[21];
    p.l2b = (const float*)d_in[22];
    p.niw = (const float*)d_in[23];
    p.nib = (const float*)d_in[24];
    p.ng = (const float*)d_in[25];
    p.nb = (const float*)d_in[26];
    p.b1a = (const float*)d_in[28];
    p.b1b = (const float*)d_in[30];
    p.hb1b = (const float*)d_in[32];
    p.b2a = (const float*)d_in[34];
    p.b2b = (const float*)d_in[36];
    p.hb2b1 = (const float*)d_in[38];
    p.hw2 = (const float*)d_in[39];
    p.hb2b2 = (const float*)d_in[40];
    p.out = (float*)d_out;

    mixer_main<<<ROWSG / RB, 256, 0, stream>>>(p);
}

// Round 6
// 436.863 us; speedup vs baseline: 2.0931x; 1.0059x over previous
//
#include <hip/hip_runtime.h>
#include <hip/hip_bf16.h>

typedef __bf16 bf16x8 __attribute__((ext_vector_type(8)));
typedef __bf16 bf16x4 __attribute__((ext_vector_type(4)));
typedef float f32x4 __attribute__((ext_vector_type(4)));

#define ROWSG 32768          // B*T
#define RB 8                 // bt rows per block
#define HPAD 72              // bf16 row stride (16B-aligned, bank-staggered)
#define NN_OFF ((size_t)ROWSG)
#define EYE_OFF ((size_t)ROWSG + (size_t)ROWSG*64)

// weight-cache offsets (bf16 elements), all WT[n][k] row-major, stride = Kp
#define OFF_EW1   0          // 64 x 224 (K=200 zero-padded)
#define OFF_EW2   14336      // 64 x 64
#define OFF_WQ    18432
#define OFF_WK    22528
#define OFF_WV    26624
#define OFF_WO    30720
#define OFF_F1    34816
#define OFF_F2    38912
#define OFF_W1A   43008      // 64 x 128
#define OFF_W1B   51200      // 256 x 64
#define OFF_HB1W  67584      // 32 x 128
#define OFF_W2A   71680      // 64 x 128
#define OFF_W2B   79872      // 32 x 64
#define OFF_HB2W1 81920      // 32 x 128
#define WS_TOTAL  86016

__device__ __align__(16) __bf16 g_ws[WS_TOTAL];

#define MFMA16(a,b,c) __builtin_amdgcn_mfma_f32_16x16x32_bf16(a,b,c,0,0,0)

// ---------------- weight transform kernel ----------------
struct TP { const float* src[14]; };

__global__ __launch_bounds__(256) void wtrans(TP tp) {
    const int gid = blockIdx.x * 256 + threadIdx.x;
    if (gid >= WS_TOTAL) return;
    const int OFFS[14] = {OFF_EW1, OFF_EW2, OFF_WQ, OFF_WK, OFF_WV, OFF_WO, OFF_F1,
                          OFF_F2, OFF_W1A, OFF_W1B, OFF_HB1W, OFF_W2A, OFF_W2B, OFF_HB2W1};
    const int KPS[14]  = {224, 64, 64, 64, 64, 64, 64, 64, 128, 64, 128, 128, 64, 128};
    const int KRS[14]  = {200, 64, 64, 64, 64, 64, 64, 64, 128, 64, 128, 128, 64, 128};
    const int NS[14]   = {64, 64, 64, 64, 64, 64, 64, 64, 64, 256, 32, 64, 32, 32};
    int m = 0;
#pragma unroll
    for (int i = 1; i < 14; ++i) if (gid >= OFFS[i]) m = i;
    const int loc = gid - OFFS[m];
    const int Kp = KPS[m];
    const int n = loc / Kp;
    const int k = loc - n * Kp;
    float v = 0.f;
    if (k < KRS[m]) v = tp.src[m][(size_t)k * NS[m] + n];   // src is W[k][n]
    g_ws[gid] = (__bf16)v;
}

// ---------------- main fused kernel ----------------
struct MainP {
    const float *qvals, *states, *hid, *eb1, *eb2, *bq, *bk, *bv, *bo,
        *l1g, *l1b, *fb1, *fb2, *l2g, *l2b, *niw, *nib, *ng, *nb,
        *b1a, *b1b, *hb1b, *b2a, *b2b, *hb2b1, *hw2, *hb2b2;
    float* out;
};

// fused projection + bias + residual + LayerNorm, in MFMA C/D register layout.
__device__ __forceinline__ void proj_ln(const __bf16* A, const __bf16* WT,
                                        const float* bias, const float* g, const float* bb,
                                        __bf16* H, int w, int quad, int l15) {
    for (int mti = 0; mti < 2; ++mti) {
        const int mt = w + 4 * mti;          // wave-uniform
        if (mt >= 5) continue;
        f32x4 acc0 = {0,0,0,0}, acc1 = {0,0,0,0}, acc2 = {0,0,0,0}, acc3 = {0,0,0,0};
#pragma unroll
        for (int ks = 0; ks < 2; ++ks) {
            const int kk = ks * 32 + quad * 8;
            const bf16x8 af = *(const bf16x8*)(A + (mt * 16 + l15) * HPAD + kk);
            acc0 = MFMA16(af, *(const bf16x8*)(WT + (size_t)(0 * 16 + l15) * 64 + kk), acc0);
            acc1 = MFMA16(af, *(const bf16x8*)(WT + (size_t)(1 * 16 + l15) * 64 + kk), acc1);
            acc2 = MFMA16(af, *(const bf16x8*)(WT + (size_t)(2 * 16 + l15) * 64 + kk), acc2);
            acc3 = MFMA16(af, *(const bf16x8*)(WT + (size_t)(3 * 16 + l15) * 64 + kk), acc3);
        }
        float v[4][4], g4[4], b4[4];
#pragma unroll
        for (int nt = 0; nt < 4; ++nt) {
            const int col = nt * 16 + l15;
            const float bo = bias[col];
            g4[nt] = g[col]; b4[nt] = bb[col];
            const f32x4 a = (nt == 0) ? acc0 : (nt == 1) ? acc1 : (nt == 2) ? acc2 : acc3;
#pragma unroll
            for (int r = 0; r < 4; ++r)
                v[nt][r] = a[r] + bo + (float)H[(mt * 16 + quad * 4 + r) * HPAD + col];
        }
#pragma unroll
        for (int r = 0; r < 4; ++r) {
            float s  = v[0][r] + v[1][r] + v[2][r] + v[3][r];
            float s2 = v[0][r]*v[0][r] + v[1][r]*v[1][r] + v[2][r]*v[2][r] + v[3][r]*v[3][r];
#pragma unroll
            for (int off = 1; off < 16; off <<= 1) {
                s  += __shfl_xor(s,  off, 64);
                s2 += __shfl_xor(s2, off, 64);
            }
            const float mu  = s * 0.015625f;
            const float var = s2 * 0.015625f - mu * mu;
            const float rs  = rsqrtf(var + 1e-5f);
#pragma unroll
            for (int nt = 0; nt < 4; ++nt)
                H[(mt * 16 + quad * 4 + r) * HPAD + nt * 16 + l15] =
                    (__bf16)((v[nt][r] - mu) * rs * g4[nt] + b4[nt]);
        }
    }
}

__global__ __launch_bounds__(256) void mixer_main(MainP p) {
    __shared__ __align__(16) __bf16 Hb[80 * HPAD];   // h -> h2 -> h3
    __shared__ __align__(16) __bf16 Qb[80 * HPAD];   // q -> attv
    __shared__ __align__(16) __bf16 Kb[80 * HPAD];   // k -> ah -> ffn hidden
    __shared__ __align__(16) __bf16 EbU[16 * HPAD];  // e -> sNi(float[512]) -> Tb1
    __shared__ __align__(16) __bf16 Tb2[16 * HPAD];
    __shared__ __align__(16) __bf16 ensB[16 * 136];
    __shared__ float  attU[8 * 81];                  // att probs -> Nf(float[512])
    __shared__ float  sQv[64];
    __shared__ float  qniL[64];
    __shared__ __align__(16) __bf16 W1bS[8 * 256];   // P10 w1; aliased as Sb (8x224) in P0/P1
    __shared__ float  B1f[8 * 32], W2f[8 * 32], T3f[8 * 32];
    // static LDS ~53.8 KB -> 3 blocks/CU (was 64KB -> 2)

    const int blk = blockIdx.x;
    const int bt0 = blk * RB;
    const int t = threadIdx.x;
    const int w = t >> 6, lane = t & 63, quad = lane >> 4, l15 = lane & 15;
    const __bf16* ws = g_ws;
    __bf16* Sb = W1bS;   // states staging: 8 rows x 224 bf16 (1792 <= 2048)

    // ---- P0: stage hidden_state -> Hb; states -> Sb (bf16, zero-padded); qvals ----
#pragma unroll
    for (int it = 0; it < 4; ++it) {
        const int u = it * 256 + t;               // 1024 float4 units (exactly RB*512 floats)
        const int x = u >> 7, rem = u & 127, n = rem >> 4, d4 = (rem & 15) * 4;
        const float4 v4 = *(const float4*)(p.hid + ((size_t)(bt0 + x) * 512 + n * 64 + d4));
        bf16x4 o; o[0] = (__bf16)v4.x; o[1] = (__bf16)v4.y; o[2] = (__bf16)v4.z; o[3] = (__bf16)v4.w;
        *(bf16x4*)(Hb + (x * 9 + n) * HPAD + d4) = o;
    }
#pragma unroll
    for (int it = 0; it < 2; ++it) {
        const int u = it * 256 + t;               // 400 float4 units = 8 rows x 200 floats
        if (u < 400) {
            const int xr = u / 50, c4 = u - xr * 50;
            const float4 v4 = *(const float4*)(p.states + (size_t)(bt0 + xr) * 200 + c4 * 4);
            bf16x4 o; o[0] = (__bf16)v4.x; o[1] = (__bf16)v4.y; o[2] = (__bf16)v4.z; o[3] = (__bf16)v4.w;
            *(bf16x4*)(Sb + xr * 224 + c4 * 4) = o;
        }
    }
    if (t < 192) { const int xr = t / 24, c = t - xr * 24; Sb[xr * 224 + 200 + c] = (__bf16)0.0f; }
    if (t < 64) sQv[t] = p.qvals[(size_t)(bt0 + (t >> 3)) * 8 + (t & 7)];
    __syncthreads();

    // ---- P1: encoder layer 1 via MFMA from Sb (row clamp: lanes 8..15 dup row 7) ----
    float e4[4];
    {
        const int n0 = w * 16;
        const int srow = (l15 < 8) ? l15 : 7;
        f32x4 acc = {0, 0, 0, 0};
        for (int ks = 0; ks < 7; ++ks) {
            const int kk = ks * 32 + quad * 8;
            const bf16x8 af = *(const bf16x8*)(Sb + srow * 224 + kk);
            const bf16x8 bf = *(const bf16x8*)(ws + OFF_EW1 + (size_t)(n0 + l15) * 224 + kk);
            acc = MFMA16(af, bf, acc);
        }
        const float b1 = p.eb1[n0 + l15];
#pragma unroll
        for (int r = 0; r < 4; ++r) {
            const float ev = fmaxf(acc[r] + b1, 0.f);
            e4[r] = ev;
            EbU[(quad * 4 + r) * HPAD + n0 + l15] = (__bf16)ev;
        }
    }
    __syncthreads();

    // ---- P2: enc = tanh(e@W2 + e + b2) -> Hb row x*9+8, ensB[:,0:64] ----
    {
        const int n0 = w * 16;
        f32x4 acc = {0, 0, 0, 0};
#pragma unroll
        for (int ks = 0; ks < 2; ++ks) {
            const int kk = ks * 32 + quad * 8;
            const bf16x8 af = *(const bf16x8*)(EbU + l15 * HPAD + kk);
            const bf16x8 bf = *(const bf16x8*)(ws + OFF_EW2 + (size_t)(n0 + l15) * 64 + kk);
            acc = MFMA16(af, bf, acc);
        }
        const float b2 = p.eb2[n0 + l15];
#pragma unroll
        for (int r = 0; r < 4; ++r) {
            const int xr = quad * 4 + r;
            if (xr < RB) {
                const float ev = tanhf(acc[r] + e4[r] + b2);
                Hb[(xr * 9 + 8) * HPAD + n0 + l15] = (__bf16)ev;
                ensB[xr * 136 + n0 + l15] = (__bf16)ev;
            }
        }
    }
    __syncthreads();

    // ---- P3: Q,K projections only (40 tile-jobs, 10 per wave); V is folded past attention ----
    for (int it = 0; it < 10; ++it) {
        const int j = w + 4 * it;                 // 0..39
        const int mat = j / 20, r20 = j % 20, mt = r20 >> 2, nt = r20 & 3;
        const __bf16* wt = ws + (mat == 0 ? OFF_WQ : OFF_WK);
        const float* bias = (mat == 0 ? p.bq : p.bk);
        __bf16* dst = (mat == 0 ? Qb : Kb);
        f32x4 acc = {0, 0, 0, 0};
#pragma unroll
        for (int ks = 0; ks < 2; ++ks) {
            const int kk = ks * 32 + quad * 8;
            const bf16x8 af = *(const bf16x8*)(Hb + (mt * 16 + l15) * HPAD + kk);
            const bf16x8 bf = *(const bf16x8*)(wt + (size_t)(nt * 16 + l15) * 64 + kk);
            acc = MFMA16(af, bf, acc);
        }
        const float bv = bias[nt * 16 + l15];
#pragma unroll
        for (int r = 0; r < 4; ++r)
            dst[(mt * 16 + quad * 4 + r) * HPAD + nt * 16 + l15] = (__bf16)(acc[r] + bv);
    }
    __syncthreads();

    // ---- P4: S = Q K^T via MFMA (A=Q rows, B=K rows), softmax in C-layout registers ----
    // wave w owns x = 2w, 2w+1. C[i][j]: i = quad*4+r, j = l15. cols j>=9 masked.
    for (int xi = 0; xi < 2; ++xi) {
        const int x = w * 2 + xi;
        const int arow = (x * 9 + l15) * HPAD;    // rows beyond i<9 are garbage -> discarded
        f32x4 acc = {0, 0, 0, 0};
#pragma unroll
        for (int ks = 0; ks < 2; ++ks) {
            const int kk = ks * 32 + quad * 8;
            const bf16x8 qa = *(const bf16x8*)(Qb + arow + kk);
            const bf16x8 kb = *(const bf16x8*)(Kb + arow + kk);
            acc = MFMA16(qa, kb, acc);
        }
#pragma unroll
        for (int r = 0; r < 4; ++r) {
            const int i = quad * 4 + r;
            float s = (l15 < 9) ? acc[r] * 0.125f : -3.0e38f;
            float m = s;
#pragma unroll
            for (int off = 1; off < 16; off <<= 1) m = fmaxf(m, __shfl_xor(m, off, 64));
            float e = (l15 < 9) ? __expf(s - m) : 0.f;
            float sum = e;
#pragma unroll
            for (int off = 1; off < 16; off <<= 1) sum += __shfl_xor(sum, off, 64);
            const float pv = e / sum;
            if (i < 9 && l15 < 9) attU[x * 81 + i * 9 + l15] = pv;
        }
    }
    __syncthreads();

    // ---- P5: ah = att @ h -> Kb (V eliminated: att@(h wv + bv) == (att@h) wv + bv) ----
    for (int xi = 0; xi < 2; ++xi) {
        const int x = w * 2 + xi;
        float vreg[9];
#pragma unroll
        for (int jj = 0; jj < 9; ++jj) vreg[jj] = (float)Hb[(x * 9 + jj) * HPAD + lane];
#pragma unroll
        for (int i = 0; i < 9; ++i) {
            float a = 0.f;
#pragma unroll
            for (int jj = 0; jj < 9; ++jj) a += attU[x * 81 + i * 9 + jj] * vreg[jj];
            Kb[(x * 9 + i) * HPAD + lane] = (__bf16)a;
        }
    }
    __syncthreads();

    // ---- P6a: attv = ah @ wv + bv -> Qb (20 tile-jobs, 5 per wave) ----
    for (int it = 0; it < 5; ++it) {
        const int j = w + 4 * it;
        const int mt = j >> 2, nt = j & 3;
        f32x4 acc = {0, 0, 0, 0};
#pragma unroll
        for (int ks = 0; ks < 2; ++ks) {
            const int kk = ks * 32 + quad * 8;
            const bf16x8 af = *(const bf16x8*)(Kb + (mt * 16 + l15) * HPAD + kk);
            const bf16x8 bf = *(const bf16x8*)(ws + OFF_WV + (size_t)(nt * 16 + l15) * 64 + kk);
            acc = MFMA16(af, bf, acc);
        }
        const float bv = p.bv[nt * 16 + l15];
#pragma unroll
        for (int r = 0; r < 4; ++r)
            Qb[(mt * 16 + quad * 4 + r) * HPAD + nt * 16 + l15] = (__bf16)(acc[r] + bv);
    }
    __syncthreads();

    // ---- P6b: o-proj + residual(h) + LN1 -> h2 in Hb ----
    proj_ln(Qb, ws + OFF_WO, p.bo, p.l1g, p.l1b, Hb, w, quad, l15);
    __syncthreads();

    // ---- P7: FFN1: f = relu(h2@W1 + b1) -> Kb ----
    for (int it = 0; it < 5; ++it) {
        const int j = w + 4 * it;
        const int mt = j >> 2, nt = j & 3;
        f32x4 acc = {0, 0, 0, 0};
#pragma unroll
        for (int ks = 0; ks < 2; ++ks) {
            const int kk = ks * 32 + quad * 8;
            const bf16x8 af = *(const bf16x8*)(Hb + (mt * 16 + l15) * HPAD + kk);
            const bf16x8 bf = *(const bf16x8*)(ws + OFF_F1 + (size_t)(nt * 16 + l15) * 64 + kk);
            acc = MFMA16(af, bf, acc);
        }
        const float fb = p.fb1[nt * 16 + l15];
#pragma unroll
        for (int r = 0; r < 4; ++r)
            Kb[(mt * 16 + quad * 4 + r) * HPAD + nt * 16 + l15] = (__bf16)fmaxf(acc[r] + fb, 0.f);
    }
    __syncthreads();

    // ---- P8: FFN2 + residual(h2) + LN2 -> h3 in Hb ----
    proj_ln(Kb, ws + OFF_F2, p.fb2, p.l2g, p.l2b, Hb, w, quad, l15);
    __syncthreads();

    // ---- P8b: ens second half = mean over 8 heads of h3 ----
#pragma unroll
    for (int it = 0; it < 2; ++it) {
        const int id = it * 256 + t;
        const int x = id >> 6, col = id & 63;
        float s = 0.f;
#pragma unroll
        for (int i = 0; i < 8; ++i) s += (float)Hb[(x * 9 + i) * HPAD + col];
        ensB[x * 136 + 64 + col] = (__bf16)(s * 0.125f);
    }
    __syncthreads();

    // ---- P9: ni = sigmoid(LN7(h3[:, :8]@fc2ni + b)); 4 threads per (x,n) split over d ----
    {
        const int pr = t >> 2, q4 = t & 3;
        const int x = pr >> 3, n = pr & 7;
        float acc[7] = {0.f, 0.f, 0.f, 0.f, 0.f, 0.f, 0.f};
        const float* wni = p.niw + n * 448;
        for (int dd = 0; dd < 16; ++dd) {
            const int d = q4 * 16 + dd;
            const float hv = (float)Hb[(x * 9 + n) * HPAD + d];
#pragma unroll
            for (int e = 0; e < 7; ++e) acc[e] += hv * wni[d * 7 + e];
        }
#pragma unroll
        for (int e = 0; e < 7; ++e) {
            acc[e] += __shfl_xor(acc[e], 1, 64);
            acc[e] += __shfl_xor(acc[e], 2, 64);
        }
        if (q4 == 0) {
            float s = 0.f;
#pragma unroll
            for (int e = 0; e < 7; ++e) { acc[e] += p.nib[n * 7 + e]; s += acc[e]; }
            const float mu = s * (1.f / 7.f);
            float s2 = 0.f;
#pragma unroll
            for (int e = 0; e < 7; ++e) { const float d0 = acc[e] - mu; s2 += d0 * d0; }
            const float rs = rsqrtf(s2 * (1.f / 7.f) + 1e-5f);
            float* sNi = (float*)EbU;
#pragma unroll
            for (int e = 0; e < 7; ++e) {
                const float vv = (acc[e] - mu) * rs * p.ng[e] + p.nb[e];
                sNi[x * 64 + n * 8 + e] = 1.f / (1.f + __expf(-vv));
            }
        }
    }
    __syncthreads();

    // ---- P9b: N_nn + eye_mask outputs, then q_ni ----
    {
        const float* sNi = (const float*)EbU;
        float* Nf = attU;
#pragma unroll
        for (int it = 0; it < 2; ++it) {
            const int id = it * 256 + t;
            const int x = id >> 6, rem = id & 63, i = rem >> 3, jj = rem & 7;
            const float nf = (i == jj) ? 1.f : sNi[x * 64 + i * 8 + (jj - (jj > i ? 1 : 0))];
            p.out[NN_OFF + (size_t)(bt0 + x) * 64 + rem] = nf;
            p.out[EYE_OFF + (size_t)(bt0 + x) * 64 + rem] = (i == jj) ? 1.f : 0.f;
            Nf[x * 64 + rem] = nf;
        }
    }
    __syncthreads();
    {
        const float* Nf = attU;
        const int pr = t >> 2, q4 = t & 3;
        const int x = pr >> 3, i = pr & 7;
        const int j0 = q4 * 2;
        float s = sQv[x * 8 + j0] * Nf[x * 64 + i * 8 + j0] +
                  sQv[x * 8 + j0 + 1] * Nf[x * 64 + i * 8 + j0 + 1];
        s += __shfl_xor(s, 1, 64);
        s += __shfl_xor(s, 2, 64);
        if (q4 == 0) qniL[x * 8 + i] = s;
    }
    __syncthreads();

    // ---- P10 sub1: t1 = relu(ens@w1a+b1a) -> Tb1(EbU); t2 = relu(ens@w2a+b2a) -> Tb2 ----
    {
        const int n0 = w * 16;
#pragma unroll
        for (int m2 = 0; m2 < 2; ++m2) {
            const __bf16* wt = ws + (m2 == 0 ? OFF_W1A : OFF_W2A);
            const float* bias = m2 == 0 ? p.b1a : p.b2a;
            __bf16* dst = m2 == 0 ? EbU : Tb2;
            f32x4 acc = {0, 0, 0, 0};
#pragma unroll
            for (int ks = 0; ks < 4; ++ks) {
                const int kk = ks * 32 + quad * 8;
                const bf16x8 af = *(const bf16x8*)(ensB + l15 * 136 + kk);
                const bf16x8 bf = *(const bf16x8*)(wt + (size_t)(n0 + l15) * 128 + kk);
                acc = MFMA16(af, bf, acc);
            }
            const float bb = bias[n0 + l15];
#pragma unroll
            for (int r = 0; r < 4; ++r)
                dst[(quad * 4 + r) * HPAD + n0 + l15] = (__bf16)fmaxf(acc[r] + bb, 0.f);
        }
    }
    __syncthreads();

    // ---- P10 sub2: w1 (16 jobs), b1 (2), w2 (2), t3 (2) = 22 tile-jobs ----
    for (int it = 0; it < 6; ++it) {
        const int j = w + 4 * it;
        if (j >= 22) continue;
        int mode, n0, Kp, ksteps, aStride;
        const __bf16 *A, *WT; const float* bias;
        if (j < 16)      { mode = 0; n0 = j * 16;        A = EbU;  aStride = HPAD; WT = ws + OFF_W1B;   bias = p.b1b;  Kp = 64;  ksteps = 2; }
        else if (j < 18) { mode = 1; n0 = (j - 16) * 16; A = ensB; aStride = 136;  WT = ws + OFF_HB1W;  bias = p.hb1b; Kp = 128; ksteps = 4; }
        else if (j < 20) { mode = 2; n0 = (j - 18) * 16; A = Tb2;  aStride = HPAD; WT = ws + OFF_W2B;   bias = p.b2b;  Kp = 64;  ksteps = 2; }
        else             { mode = 3; n0 = (j - 20) * 16; A = ensB; aStride = 136;  WT = ws + OFF_HB2W1; bias = p.hb2b1;Kp = 128; ksteps = 4; }
        f32x4 acc = {0, 0, 0, 0};
        for (int ks = 0; ks < ksteps; ++ks) {
            const int kk = ks * 32 + quad * 8;
            const bf16x8 af = *(const bf16x8*)(A + l15 * aStride + kk);
            const bf16x8 bf = *(const bf16x8*)(WT + (size_t)(n0 + l15) * Kp + kk);
            acc = MFMA16(af, bf, acc);
        }
        const float bb = bias[n0 + l15];
#pragma unroll
        for (int r = 0; r < 4; ++r) {
            const int xr = quad * 4 + r;
            if (xr < RB) {
                const float val = acc[r] + bb;
                if (mode == 0)      W1bS[xr * 256 + n0 + l15] = (__bf16)fabsf(val);
                else if (mode == 1) B1f[xr * 32 + n0 + l15] = val;
                else if (mode == 2) W2f[xr * 32 + n0 + l15] = fabsf(val);
                else                T3f[xr * 32 + n0 + l15] = fmaxf(val, 0.f);
            }
        }
    }
    __syncthreads();

    // ---- P11: hidden = elu(q_ni@w1 + b1); y = hidden@w2 + b2 ----
    if (t < 128) {
        const int x = t >> 4, sub = t & 15;
        float pp = 0.f, pb = 0.f;
#pragma unroll
        for (int h2i = 0; h2i < 2; ++h2i) {
            const int e = sub + h2i * 16;
            float a = B1f[x * 32 + e];
#pragma unroll
            for (int i = 0; i < 8; ++i) a += qniL[x * 8 + i] * (float)W1bS[x * 256 + i * 32 + e];
            const float hid = a > 0.f ? a : (__expf(a) - 1.f);
            pp += hid * W2f[x * 32 + e];
            pb += T3f[x * 32 + e] * p.hw2[e];
        }
#pragma unroll
        for (int off = 1; off < 16; off <<= 1) {
            pp += __shfl_xor(pp, off, 64);
            pb += __shfl_xor(pb, off, 64);
        }
        if (sub == 0) p.out[bt0 + x] = pp + pb + p.hb2b2[0];
    }
}

extern "C" void kernel_launch(void* const* d_in, const int* in_sizes, int n_in,
                              void* d_out, int out_size, void* d_ws, size_t ws_size,
                              hipStream_t stream) {
    TP tp;
    tp.src[0]  = (const float*)d_in[3];   // enc_w1
    tp.src[1]  = (const float*)d_in[5];   // enc_w2
    tp.src[2]  = (const float*)d_in[7];   // wq
    tp.src[3]  = (const float*)d_in[9];   // wk
    tp.src[4]  = (const float*)d_in[11];  // wv
    tp.src[5]  = (const float*)d_in[13];  // wo
    tp.src[6]  = (const float*)d_in[17];  // ffn_w1
    tp.src[7]  = (const float*)d_in[19];  // ffn_w2
    tp.src[8]  = (const float*)d_in[27];  // w1a
    tp.src[9]  = (const float*)d_in[29];  // w1b
    tp.src[10] = (const float*)d_in[31];  // hb1w
    tp.src[11] = (const float*)d_in[33];  // w2a
    tp.src[12] = (const float*)d_in[35];  // w2b
    tp.src[13] = (const float*)d_in[37];  // hb2w1
    wtrans<<<(WS_TOTAL + 255) / 256, 256, 0, stream>>>(tp);

    MainP p;
    p.qvals = (const float*)d_in[0];
    p.states = (const float*)d_in[1];
    p.hid = (const float*)d_in[2];
    p.eb1 = (const float*)d_in[4];
    p.eb2 = (const float*)d_in[6];
    p.bq = (const float*)d_in[8];
    p.bk = (const float*)d_in[10];
    p.bv = (const float*)d_in[12];
    p.bo = (const float*)d_in[14];
    p.l1g = (const float*)d_in[15];
    p.l1b = (const float*)d_in[16];
    p.fb1 = (const float*)d_in[18];
    p.fb2 = (const float*)d_in[20];
    p.l2g = (const float*)d_in[21];
    p.l2b = (const float*)d_in[22];
    p.niw = (const float*)d_in[23];
    p.nib = (const float*)d_in[24];
    p.ng = (const float*)d_in[25];
    p.nb = (const float*)d_in[26];
    p.b1a = (const float*)d_in[28];
    p.b1b = (const float*)d_in[30];
    p.hb1b = (const float*)d_in[32];
    p.b2a = (const float*)d_in[34];
    p.b2b = (const float*)d_in[36];
    p.hb2b1 = (const float*)d_in[38];
    p.hw2 = (const float*)d_in[39];
    p.hb2b2 = (const float*)d_in[40];
    p.out = (float*)d_out;

    mixer_main<<<ROWSG / RB, 256, 0, stream>>>(p);
}